// Round 1
// baseline (1165.926 us; speedup 1.0000x reference)
//
#include <hip/hip_runtime.h>
#include <cstdint>
#include <cstddef>

#define FIN 500
#define FH  128
#define FOUT 40

// ---------------- CSR build ----------------

__global__ void k_hist(const int* __restrict__ dst, int* __restrict__ cnt, int E) {
  int e = blockIdx.x * 256 + threadIdx.x;
  if (e < E) atomicAdd(&cnt[dst[e]], 1);
}

__global__ void k_dis(const int* __restrict__ cnt, float* __restrict__ dis, int n) {
  int i = blockIdx.x * 256 + threadIdx.x;
  if (i < n) dis[i] = rsqrtf((float)cnt[i] + 1.0f);  // deg includes self-loop
}

// block scans 1024 elements (256 thr x 4); writes local-exclusive prefix + block sum
__global__ void k_scan1(const int* __restrict__ cnt, int* __restrict__ rp,
                        int* __restrict__ bsums, int n) {
  __shared__ int sums[256];
  int t = threadIdx.x;
  int base = blockIdx.x * 1024;
  int c[4]; int tot = 0;
#pragma unroll
  for (int j = 0; j < 4; ++j) {
    int idx = base + t * 4 + j;
    c[j] = (idx < n) ? cnt[idx] : 0;
    tot += c[j];
  }
  sums[t] = tot;
  __syncthreads();
  for (int off = 1; off < 256; off <<= 1) {
    int v = 0;
    if (t >= off) v = sums[t - off];
    __syncthreads();
    if (t >= off) sums[t] += v;
    __syncthreads();
  }
  int run = sums[t] - tot;
#pragma unroll
  for (int j = 0; j < 4; ++j) {
    int idx = base + t * 4 + j;
    if (idx < n) rp[idx] = run;
    run += c[j];
  }
  if (t == 255) bsums[blockIdx.x] = sums[255];
}

__global__ void k_scan2(int* __restrict__ bsums, int nb) {
  __shared__ int s[256];
  int t = threadIdx.x;
  int v = (t < nb) ? bsums[t] : 0;
  s[t] = v;
  __syncthreads();
  for (int off = 1; off < 256; off <<= 1) {
    int u = 0;
    if (t >= off) u = s[t - off];
    __syncthreads();
    if (t >= off) s[t] += u;
    __syncthreads();
  }
  if (t < nb) bsums[t] = s[t] - v;  // exclusive
}

__global__ void k_scan3(int* __restrict__ rp, const int* __restrict__ bsums, int n, int E) {
  int idx = blockIdx.x * 256 + threadIdx.x;
  if (idx < n) rp[idx] += bsums[idx >> 10];
  if (idx == n) rp[n] = E;
}

__global__ void k_scatter(const int* __restrict__ src, const int* __restrict__ dst,
                          const float* __restrict__ dis,
                          const int* __restrict__ rp, int* __restrict__ fill,
                          int* __restrict__ src_sorted, float* __restrict__ norm_sorted,
                          int E) {
  int e = blockIdx.x * 256 + threadIdx.x;
  if (e >= E) return;
  int d = dst[e], s = src[e];
  int pos = rp[d] + atomicAdd(&fill[d], 1);
  src_sorted[pos] = s;
  norm_sorted[pos] = dis[s] * dis[d];
}

// ---------------- fp32 GEMM: C[M][128] = A[M][K] @ W[K][128] ----------------
// BM=64, BN=128, BK=16, 256 threads, each thread 8 rows x 4 cols.

__global__ void __launch_bounds__(256) k_gemm(const float* __restrict__ A,
                                              const float* __restrict__ W,
                                              float* __restrict__ C,
                                              int M, int K) {
  __shared__ float As[16][68];   // [k][m], padded: stride 68 floats = 272B (16B-aligned rows)
  __shared__ float Ws[16][128];  // [k][n]
  int tid = threadIdx.x;
  int blockRow = blockIdx.x * 64;
  int tn = tid & 31;   // col group: cols tn*4 .. tn*4+3
  int tm = tid >> 5;   // row group: rows tm*8 .. tm*8+7

  float acc[8][4] = {{0.f}};

  int kTiles = (K + 15) / 16;
  for (int kt = 0; kt < kTiles; ++kt) {
    int k0 = kt * 16;
    // load A tile: 64x16
    {
      int kk = tid & 15;
      int r0 = tid >> 4;
#pragma unroll
      for (int p = 0; p < 4; ++p) {
        int r = r0 + p * 16;
        int gr = blockRow + r;
        int gk = k0 + kk;
        float v = 0.f;
        if (gr < M && gk < K) v = A[(size_t)gr * K + gk];
        As[kk][r] = v;
      }
    }
    // load W tile: 16x128
    {
      int col = tid & 127;
      int kr0 = tid >> 7;
#pragma unroll
      for (int p = 0; p < 8; ++p) {
        int kr = kr0 + p * 2;
        int gk = k0 + kr;
        Ws[kr][col] = (gk < K) ? W[(size_t)gk * 128 + col] : 0.f;
      }
    }
    __syncthreads();
#pragma unroll
    for (int kk = 0; kk < 16; ++kk) {
      float4 a0 = *reinterpret_cast<const float4*>(&As[kk][tm * 8]);
      float4 a1 = *reinterpret_cast<const float4*>(&As[kk][tm * 8 + 4]);
      float4 w  = *reinterpret_cast<const float4*>(&Ws[kk][tn * 4]);
      float a[8] = {a0.x, a0.y, a0.z, a0.w, a1.x, a1.y, a1.z, a1.w};
      float wv[4] = {w.x, w.y, w.z, w.w};
#pragma unroll
      for (int i = 0; i < 8; ++i)
#pragma unroll
        for (int j = 0; j < 4; ++j)
          acc[i][j] += a[i] * wv[j];
    }
    __syncthreads();
  }
#pragma unroll
  for (int i = 0; i < 8; ++i) {
    int gr = blockRow + tm * 8 + i;
    if (gr < M) {
      float4 v = {acc[i][0], acc[i][1], acc[i][2], acc[i][3]};
      *reinterpret_cast<float4*>(&C[(size_t)gr * 128 + tn * 4]) = v;
    }
  }
}

// ---------------- aggregation: out = relu(sum_e norm*h[src] + deg^-1 * h[i] + b) ----------------

__global__ void __launch_bounds__(128) k_agg(const float* __restrict__ h,
                                             float* __restrict__ out,
                                             const float* __restrict__ dis,
                                             const int* __restrict__ rp,
                                             const int* __restrict__ src_sorted,
                                             const float* __restrict__ norm_sorted,
                                             const float* __restrict__ bias) {
  int i = blockIdx.x;
  int f = threadIdx.x;
  float di = dis[i];
  float acc = di * di * h[(size_t)i * FH + f];
  int e = rp[i], end = rp[i + 1];
  for (; e + 1 < end; e += 2) {
    int s0 = src_sorted[e], s1 = src_sorted[e + 1];
    float n0 = norm_sorted[e], n1 = norm_sorted[e + 1];
    acc += n0 * h[(size_t)s0 * FH + f];
    acc += n1 * h[(size_t)s1 * FH + f];
  }
  if (e < end) {
    int s0 = src_sorted[e];
    acc += norm_sorted[e] * h[(size_t)s0 * FH + f];
  }
  out[(size_t)i * FH + f] = fmaxf(acc + bias[f], 0.0f);
}

// ---------------- fused logits + log_softmax (one wave per node) ----------------

__global__ void __launch_bounds__(64) k_logits(const float* __restrict__ h,
                                               const float* __restrict__ Wfc,
                                               const float* __restrict__ bfc,
                                               float* __restrict__ out) {
  int i = blockIdx.x;
  int l = threadIdx.x;
  __shared__ float hs[FH];
  hs[l] = h[(size_t)i * FH + l];
  hs[l + 64] = h[(size_t)i * FH + 64 + l];
  __syncthreads();
  float logit = -INFINITY;
  if (l < FOUT) {
    float acc = bfc[l];
#pragma unroll 8
    for (int k = 0; k < FH; ++k) acc += hs[k] * Wfc[k * FOUT + l];
    logit = acc;
  }
  float m = logit;
#pragma unroll
  for (int s = 32; s; s >>= 1) m = fmaxf(m, __shfl_xor(m, s));
  float ex = (l < FOUT) ? expf(logit - m) : 0.0f;
  float ss = ex;
#pragma unroll
  for (int s = 32; s; s >>= 1) ss += __shfl_xor(ss, s);
  if (l < FOUT) out[(size_t)i * FOUT + l] = logit - m - logf(ss);
}

// ---------------- host ----------------

static inline size_t align_up(size_t x, size_t a) { return (x + a - 1) & ~(a - 1); }

extern "C" void kernel_launch(void* const* d_in, const int* in_sizes, int n_in,
                              void* d_out, int out_size, void* d_ws, size_t ws_size,
                              hipStream_t stream) {
  const float* x   = (const float*)d_in[0];
  const int*   ei  = (const int*)d_in[1];
  const float* W0  = (const float*)d_in[2];
  const float* b0  = (const float*)d_in[3];
  const float* W1  = (const float*)d_in[4];
  const float* b1  = (const float*)d_in[5];
  const float* W2  = (const float*)d_in[6];
  const float* b2  = (const float*)d_in[7];
  const float* Wfc = (const float*)d_in[8];
  const float* bfc = (const float*)d_in[9];
  float* out = (float*)d_out;

  const int N = in_sizes[0] / FIN;       // 100000
  const int E = in_sizes[1] / 2;         // 1600000
  const int* src = ei;
  const int* dst = ei + E;

  // workspace layout
  char* ws = (char*)d_ws;
  size_t off = 0;
  int* cnt = (int*)(ws + off);            off = align_up(off + (size_t)N * 4, 512);
  float* dis = (float*)(ws + off);        off = align_up(off + (size_t)N * 4, 512);
  int* rp = (int*)(ws + off);             off = align_up(off + (size_t)(N + 1) * 4, 512);
  int* bsums = (int*)(ws + off);          off = align_up(off + 4096, 512);
  int* src_sorted = (int*)(ws + off);     off = align_up(off + (size_t)E * 4, 512);
  float* norm_sorted = (float*)(ws + off);off = align_up(off + (size_t)E * 4, 512);
  float* hA = (float*)(ws + off);         off = align_up(off + (size_t)N * FH * 4, 512);
  float* hB = (float*)(ws + off);         off = align_up(off + (size_t)N * FH * 4, 512);

  const int gE = (E + 255) / 256;
  const int gN = (N + 255) / 256;
  const int nbScan = (N + 1023) / 1024;

  // --- CSR build ---
  hipMemsetAsync(cnt, 0, (size_t)N * 4, stream);
  k_hist<<<gE, 256, 0, stream>>>(dst, cnt, E);
  k_dis<<<gN, 256, 0, stream>>>(cnt, dis, N);
  k_scan1<<<nbScan, 256, 0, stream>>>(cnt, rp, bsums, N);
  k_scan2<<<1, 256, 0, stream>>>(bsums, nbScan);
  k_scan3<<<(N + 1 + 255) / 256, 256, 0, stream>>>(rp, bsums, N, E);
  hipMemsetAsync(cnt, 0, (size_t)N * 4, stream);
  k_scatter<<<gE, 256, 0, stream>>>(src, dst, dis, rp, cnt, src_sorted, norm_sorted, E);

  const int gGemm = (N + 63) / 64;

  // --- layer 0: 500 -> 128 ---
  k_gemm<<<gGemm, 256, 0, stream>>>(x, W0, hA, N, FIN);
  k_agg<<<N, 128, 0, stream>>>(hA, hB, dis, rp, src_sorted, norm_sorted, b0);
  // --- layer 1: 128 -> 128 ---
  k_gemm<<<gGemm, 256, 0, stream>>>(hB, W1, hA, N, FH);
  k_agg<<<N, 128, 0, stream>>>(hA, hB, dis, rp, src_sorted, norm_sorted, b1);
  // --- layer 2: 128 -> 128 ---
  k_gemm<<<gGemm, 256, 0, stream>>>(hB, W2, hA, N, FH);
  k_agg<<<N, 128, 0, stream>>>(hA, hB, dis, rp, src_sorted, norm_sorted, b2);
  // --- FC + log_softmax ---
  k_logits<<<N, 64, 0, stream>>>(hB, Wfc, bfc, out);
}

// Round 2
// 683.725 us; speedup vs baseline: 1.7053x; 1.7053x over previous
//
#include <hip/hip_runtime.h>
#include <hip/hip_bf16.h>
#include <cstdint>
#include <cstddef>

#define FIN 500
#define FH  128
#define FOUT 40

typedef __attribute__((ext_vector_type(8))) short short8;
typedef __attribute__((ext_vector_type(4))) float f32x4;

__device__ inline float bf_lo(unsigned v) { unsigned t = v << 16; return __builtin_bit_cast(float, t); }
__device__ inline float bf_hi(unsigned v) { unsigned t = v & 0xffff0000u; return __builtin_bit_cast(float, t); }
__device__ inline unsigned short f2bf_bits(float f) {
  __hip_bfloat16 b = __float2bfloat16(f);
  return __builtin_bit_cast(unsigned short, b);
}

// ---------------- CSR build ----------------

__global__ void k_hist(const int* __restrict__ dst, int* __restrict__ cnt, int E) {
  int e = blockIdx.x * 256 + threadIdx.x;
  if (e < E) atomicAdd(&cnt[dst[e]], 1);
}

__global__ void k_dis(const int* __restrict__ cnt, float* __restrict__ dis, int n) {
  int i = blockIdx.x * 256 + threadIdx.x;
  if (i < n) dis[i] = rsqrtf((float)cnt[i] + 1.0f);  // deg includes self-loop
}

__global__ void k_scan1(const int* __restrict__ cnt, int* __restrict__ rp,
                        int* __restrict__ bsums, int n) {
  __shared__ int sums[256];
  int t = threadIdx.x;
  int base = blockIdx.x * 1024;
  int c[4]; int tot = 0;
#pragma unroll
  for (int j = 0; j < 4; ++j) {
    int idx = base + t * 4 + j;
    c[j] = (idx < n) ? cnt[idx] : 0;
    tot += c[j];
  }
  sums[t] = tot;
  __syncthreads();
  for (int off = 1; off < 256; off <<= 1) {
    int v = 0;
    if (t >= off) v = sums[t - off];
    __syncthreads();
    if (t >= off) sums[t] += v;
    __syncthreads();
  }
  int run = sums[t] - tot;
#pragma unroll
  for (int j = 0; j < 4; ++j) {
    int idx = base + t * 4 + j;
    if (idx < n) rp[idx] = run;
    run += c[j];
  }
  if (t == 255) bsums[blockIdx.x] = sums[255];
}

__global__ void k_scan2(int* __restrict__ bsums, int nb) {
  __shared__ int s[256];
  int t = threadIdx.x;
  int v = (t < nb) ? bsums[t] : 0;
  s[t] = v;
  __syncthreads();
  for (int off = 1; off < 256; off <<= 1) {
    int u = 0;
    if (t >= off) u = s[t - off];
    __syncthreads();
    if (t >= off) s[t] += u;
    __syncthreads();
  }
  if (t < nb) bsums[t] = s[t] - v;  // exclusive
}

__global__ void k_scan3(int* __restrict__ rp, const int* __restrict__ bsums, int n, int E) {
  int idx = blockIdx.x * 256 + threadIdx.x;
  if (idx < n) rp[idx] += bsums[idx >> 10];
  if (idx == n) rp[n] = E;
}

// scatter edges to CSR order; pack (src, norm_bits) into int2
__global__ void k_scatter(const int* __restrict__ src, const int* __restrict__ dst,
                          const float* __restrict__ dis,
                          const int* __restrict__ rp, int* __restrict__ fill,
                          int2* __restrict__ epack, int E) {
  int e = blockIdx.x * 256 + threadIdx.x;
  if (e >= E) return;
  int d = dst[e], s = src[e];
  int pos = rp[d] + atomicAdd(&fill[d], 1);
  float nw = dis[s] * dis[d];
  epack[pos] = make_int2(s, __builtin_bit_cast(int, nw));
}

// ---------------- weight prep: W[K][128] f32 -> WT[128][KPAD] bf16 (zero-padded) ----------------

__global__ void k_prep_w(const float* __restrict__ W, short* __restrict__ WT, int K, int KPAD) {
  int idx = blockIdx.x * 256 + threadIdx.x;
  if (idx >= 128 * KPAD) return;
  int c = idx / KPAD, k = idx - c * KPAD;
  WT[idx] = (k < K) ? (short)f2bf_bits(W[(size_t)k * FH + c]) : (short)0;
}

// ---------------- MFMA GEMM: C[M][128](bf16) = A[M][K] @ WT^T ----------------
// BM=128, BN=128, BK=32, 256 threads (4 waves, 2x2), 16x16x32 bf16 MFMA.
// LDS tiles: 128 rows x 32 bf16, row stride 80B (5x16B units) -> b128 frag
// reads land 8 lanes per 4-bank quad (minimum-time wave64 access).

template<bool AF32>
__global__ void __launch_bounds__(256) k_gemm_mfma(const void* __restrict__ Aptr,
                                                   const short* __restrict__ WT,
                                                   short* __restrict__ C,
                                                   int M, int K, int KPAD) {
  __shared__ char smem[2 * 128 * 80];
  char* sA = smem;
  char* sB = smem + 128 * 80;
  const int tid = threadIdx.x;
  const int r0 = blockIdx.x * 128;
  const int wave = tid >> 6, lane = tid & 63;
  const int wm = wave >> 1, wn = wave & 1;
  const int lr = lane & 15, g = lane >> 4;
  const int sr = tid >> 1;   // staging row/col 0..127
  const int sh = tid & 1;    // k-half (16 elements)

  f32x4 acc[4][4];
#pragma unroll
  for (int i = 0; i < 4; ++i)
#pragma unroll
    for (int j = 0; j < 4; ++j) acc[i][j] = (f32x4){0.f, 0.f, 0.f, 0.f};

  const int nkt = (K + 31) / 32;
  for (int kt = 0; kt < nkt; ++kt) {
    const int k0 = kt * 32 + sh * 16;
    // ---- stage A (convert if fp32) ----
    short8 a0, a1;
    {
      int gr = r0 + sr;
      if (AF32) {
        const float* A = (const float*)Aptr;
        unsigned short tb[16];
        if (gr < M && k0 + 16 <= K) {
          const float4* ap = (const float4*)(A + (size_t)gr * K + k0);
          float4 f0 = ap[0], f1 = ap[1], f2 = ap[2], f3 = ap[3];
          float fv[16] = {f0.x, f0.y, f0.z, f0.w, f1.x, f1.y, f1.z, f1.w,
                          f2.x, f2.y, f2.z, f2.w, f3.x, f3.y, f3.z, f3.w};
#pragma unroll
          for (int j = 0; j < 16; ++j) tb[j] = f2bf_bits(fv[j]);
        } else {
          const float* ap = A + (size_t)gr * K;
#pragma unroll
          for (int j = 0; j < 16; ++j) {
            int gk = k0 + j;
            float v = (gr < M && gk < K) ? ap[gk] : 0.f;
            tb[j] = f2bf_bits(v);
          }
        }
#pragma unroll
        for (int j = 0; j < 8; ++j) { a0[j] = (short)tb[j]; a1[j] = (short)tb[j + 8]; }
      } else {
        const short* A = (const short*)Aptr;  // bf16, K == KPAD, k0+16 <= K
        if (gr < M) {
          const short8* ap = (const short8*)(A + (size_t)gr * K + k0);
          a0 = ap[0]; a1 = ap[1];
        } else {
          a0 = (short8){0,0,0,0,0,0,0,0}; a1 = a0;
        }
      }
      *(short8*)(sA + sr * 80 + (2 * sh) * 16) = a0;
      *(short8*)(sA + sr * 80 + (2 * sh + 1) * 16) = a1;
    }
    // ---- stage B from WT[128][KPAD] ----
    {
      const short8* wp = (const short8*)(WT + (size_t)sr * KPAD + k0);
      short8 b0 = wp[0], b1 = wp[1];
      *(short8*)(sB + sr * 80 + (2 * sh) * 16) = b0;
      *(short8*)(sB + sr * 80 + (2 * sh + 1) * 16) = b1;
    }
    __syncthreads();
    // ---- fragments + MFMA ----
    short8 af[4], bfr[4];
#pragma unroll
    for (int i = 0; i < 4; ++i)
      af[i] = *(const short8*)(sA + (wm * 64 + i * 16 + lr) * 80 + g * 16);
#pragma unroll
    for (int j = 0; j < 4; ++j)
      bfr[j] = *(const short8*)(sB + (wn * 64 + j * 16 + lr) * 80 + g * 16);
#pragma unroll
    for (int i = 0; i < 4; ++i)
#pragma unroll
      for (int j = 0; j < 4; ++j)
        acc[i][j] = __builtin_amdgcn_mfma_f32_16x16x32_bf16(af[i], bfr[j], acc[i][j], 0, 0, 0);
    __syncthreads();
  }
  // ---- epilogue: C/D layout col=lane&15, row=(lane>>4)*4+reg ----
#pragma unroll
  for (int i = 0; i < 4; ++i) {
#pragma unroll
    for (int reg = 0; reg < 4; ++reg) {
      int gr = r0 + wm * 64 + i * 16 + g * 4 + reg;
      if (gr < M) {
#pragma unroll
        for (int j = 0; j < 4; ++j) {
          int gc = wn * 64 + j * 16 + lr;
          C[(size_t)gr * FH + gc] = (short)f2bf_bits(acc[i][j][reg]);
        }
      }
    }
  }
}

// ---------------- aggregation (bf16 in/out, fp32 accum) ----------------
// one wave per node; lane covers features 2*lane, 2*lane+1 (one u32 per lane = 256B/row)

__global__ void __launch_bounds__(256) k_agg(const unsigned* __restrict__ h,   // bf16 rows as u32[64]
                                             unsigned* __restrict__ out,
                                             const float* __restrict__ dis,
                                             const int* __restrict__ rp,
                                             const int2* __restrict__ epack,
                                             const float* __restrict__ bias,
                                             int N) {
  int node = blockIdx.x * 4 + (threadIdx.x >> 6);
  int lane = threadIdx.x & 63;
  if (node >= N) return;
  float di = dis[node];
  unsigned sv = h[(size_t)node * 64 + lane];
  float w = di * di;
  float a0 = w * bf_lo(sv);
  float a1 = w * bf_hi(sv);
  int e = rp[node], end = rp[node + 1];
  for (; e + 1 < end; e += 2) {
    int2 p0 = epack[e], p1 = epack[e + 1];
    unsigned v0 = h[(size_t)p0.x * 64 + lane];
    unsigned v1 = h[(size_t)p1.x * 64 + lane];
    float n0 = __builtin_bit_cast(float, p0.y);
    float n1 = __builtin_bit_cast(float, p1.y);
    a0 += n0 * bf_lo(v0); a1 += n0 * bf_hi(v0);
    a0 += n1 * bf_lo(v1); a1 += n1 * bf_hi(v1);
  }
  if (e < end) {
    int2 p0 = epack[e];
    unsigned v0 = h[(size_t)p0.x * 64 + lane];
    float n0 = __builtin_bit_cast(float, p0.y);
    a0 += n0 * bf_lo(v0); a1 += n0 * bf_hi(v0);
  }
  a0 = fmaxf(a0 + bias[2 * lane], 0.f);
  a1 = fmaxf(a1 + bias[2 * lane + 1], 0.f);
  unsigned r = ((unsigned)f2bf_bits(a1) << 16) | (unsigned)f2bf_bits(a0);
  out[(size_t)node * 64 + lane] = r;
}

// ---------------- fused logits + log_softmax (one wave per node) ----------------

__global__ void __launch_bounds__(256) k_logits(const unsigned* __restrict__ h,  // bf16 rows
                                                const float* __restrict__ Wfc,
                                                const float* __restrict__ bfc,
                                                float* __restrict__ out, int N) {
  int node = blockIdx.x * 4 + (threadIdx.x >> 6);
  int w = threadIdx.x >> 6;
  int l = threadIdx.x & 63;
  bool valid = node < N;
  int nclamp = valid ? node : (N - 1);
  __shared__ float hs[4][128];
  unsigned v = h[(size_t)nclamp * 64 + l];
  hs[w][2 * l] = bf_lo(v);
  hs[w][2 * l + 1] = bf_hi(v);
  __syncthreads();
  float logit = -INFINITY;
  if (l < FOUT) {
    float acc = bfc[l];
#pragma unroll 8
    for (int k = 0; k < FH; ++k) acc += hs[w][k] * Wfc[k * FOUT + l];
    logit = acc;
  }
  float m = logit;
#pragma unroll
  for (int s = 32; s; s >>= 1) m = fmaxf(m, __shfl_xor(m, s));
  float ex = (l < FOUT) ? expf(logit - m) : 0.0f;
  float ss = ex;
#pragma unroll
  for (int s = 32; s; s >>= 1) ss += __shfl_xor(ss, s);
  if (valid && l < FOUT) out[(size_t)node * FOUT + l] = logit - m - logf(ss);
}

// ---------------- host ----------------

static inline size_t align_up(size_t x, size_t a) { return (x + a - 1) & ~(a - 1); }

extern "C" void kernel_launch(void* const* d_in, const int* in_sizes, int n_in,
                              void* d_out, int out_size, void* d_ws, size_t ws_size,
                              hipStream_t stream) {
  const float* x   = (const float*)d_in[0];
  const int*   ei  = (const int*)d_in[1];
  const float* W0  = (const float*)d_in[2];
  const float* b0  = (const float*)d_in[3];
  const float* W1  = (const float*)d_in[4];
  const float* b1  = (const float*)d_in[5];
  const float* W2  = (const float*)d_in[6];
  const float* b2  = (const float*)d_in[7];
  const float* Wfc = (const float*)d_in[8];
  const float* bfc = (const float*)d_in[9];
  float* out = (float*)d_out;

  const int N = in_sizes[0] / FIN;       // 100000
  const int E = in_sizes[1] / 2;         // 1600000
  const int* src = ei;
  const int* dst = ei + E;
  const int KP0 = 512;                   // FIN padded to mult of 32

  // workspace layout
  char* ws = (char*)d_ws;
  size_t off = 0;
  int* cnt = (int*)(ws + off);            off = align_up(off + (size_t)N * 4, 512);
  float* dis = (float*)(ws + off);        off = align_up(off + (size_t)N * 4, 512);
  int* rp = (int*)(ws + off);             off = align_up(off + (size_t)(N + 1) * 4, 512);
  int* bsums = (int*)(ws + off);          off = align_up(off + 4096, 512);
  int2* epack = (int2*)(ws + off);        off = align_up(off + (size_t)E * 8, 512);
  short* WT0 = (short*)(ws + off);        off = align_up(off + (size_t)128 * KP0 * 2, 512);
  short* WT1 = (short*)(ws + off);        off = align_up(off + (size_t)128 * FH * 2, 512);
  short* WT2 = (short*)(ws + off);        off = align_up(off + (size_t)128 * FH * 2, 512);
  short* hA = (short*)(ws + off);         off = align_up(off + (size_t)N * FH * 2, 512);
  short* hB = (short*)(ws + off);         off = align_up(off + (size_t)N * FH * 2, 512);

  const int gE = (E + 255) / 256;
  const int gN = (N + 255) / 256;
  const int nbScan = (N + 1023) / 1024;

  // --- CSR build ---
  hipMemsetAsync(cnt, 0, (size_t)N * 4, stream);
  k_hist<<<gE, 256, 0, stream>>>(dst, cnt, E);
  k_dis<<<gN, 256, 0, stream>>>(cnt, dis, N);
  k_scan1<<<nbScan, 256, 0, stream>>>(cnt, rp, bsums, N);
  k_scan2<<<1, 256, 0, stream>>>(bsums, nbScan);
  k_scan3<<<(N + 1 + 255) / 256, 256, 0, stream>>>(rp, bsums, N, E);
  hipMemsetAsync(cnt, 0, (size_t)N * 4, stream);
  k_scatter<<<gE, 256, 0, stream>>>(src, dst, dis, rp, cnt, epack, E);

  // --- weight prep ---
  k_prep_w<<<(128 * KP0 + 255) / 256, 256, 0, stream>>>(W0, WT0, FIN, KP0);
  k_prep_w<<<(128 * FH + 255) / 256, 256, 0, stream>>>(W1, WT1, FH, FH);
  k_prep_w<<<(128 * FH + 255) / 256, 256, 0, stream>>>(W2, WT2, FH, FH);

  const int gGemm = (N + 127) / 128;
  const int gAgg = (N + 3) / 4;

  // --- layer 0: 500 -> 128 ---
  k_gemm_mfma<true><<<gGemm, 256, 0, stream>>>(x, WT0, hA, N, FIN, KP0);
  k_agg<<<gAgg, 256, 0, stream>>>((const unsigned*)hA, (unsigned*)hB, dis, rp, epack, b0, N);
  // --- layer 1 ---
  k_gemm_mfma<false><<<gGemm, 256, 0, stream>>>(hB, WT1, hA, N, FH, FH);
  k_agg<<<gAgg, 256, 0, stream>>>((const unsigned*)hA, (unsigned*)hB, dis, rp, epack, b1, N);
  // --- layer 2 ---
  k_gemm_mfma<false><<<gGemm, 256, 0, stream>>>(hB, WT2, hA, N, FH, FH);
  k_agg<<<gAgg, 256, 0, stream>>>((const unsigned*)hA, (unsigned*)hB, dis, rp, epack, b2, N);
  // --- FC + log_softmax ---
  k_logits<<<gAgg, 256, 0, stream>>>((const unsigned*)hB, Wfc, bfc, out, N);
}

// Round 3
// 546.353 us; speedup vs baseline: 2.1340x; 1.2514x over previous
//
#include <hip/hip_runtime.h>
#include <hip/hip_bf16.h>
#include <cstdint>
#include <cstddef>

#define FIN 500
#define FH  128
#define FOUT 40

typedef __attribute__((ext_vector_type(8))) short short8;
typedef __attribute__((ext_vector_type(4))) float f32x4;

__device__ inline float bf_lo(unsigned v) { unsigned t = v << 16; return __builtin_bit_cast(float, t); }
__device__ inline float bf_hi(unsigned v) { unsigned t = v & 0xffff0000u; return __builtin_bit_cast(float, t); }
__device__ inline unsigned short f2bf_bits(float f) {
  __hip_bfloat16 b = __float2bfloat16(f);
  return __builtin_bit_cast(unsigned short, b);
}

// ---------------- CSR build ----------------

__global__ void k_hist(const int* __restrict__ dst, int* __restrict__ cnt, int E) {
  int e = blockIdx.x * 256 + threadIdx.x;
  if (e < E) atomicAdd(&cnt[dst[e]], 1);
}

__global__ void k_dis(const int* __restrict__ cnt, float* __restrict__ dis, int n) {
  int i = blockIdx.x * 256 + threadIdx.x;
  if (i < n) dis[i] = rsqrtf((float)cnt[i] + 1.0f);  // deg includes self-loop
}

__global__ void k_scan1(const int* __restrict__ cnt, int* __restrict__ rp,
                        int* __restrict__ bsums, int n) {
  __shared__ int sums[256];
  int t = threadIdx.x;
  int base = blockIdx.x * 1024;
  int c[4]; int tot = 0;
#pragma unroll
  for (int j = 0; j < 4; ++j) {
    int idx = base + t * 4 + j;
    c[j] = (idx < n) ? cnt[idx] : 0;
    tot += c[j];
  }
  sums[t] = tot;
  __syncthreads();
  for (int off = 1; off < 256; off <<= 1) {
    int v = 0;
    if (t >= off) v = sums[t - off];
    __syncthreads();
    if (t >= off) sums[t] += v;
    __syncthreads();
  }
  int run = sums[t] - tot;
#pragma unroll
  for (int j = 0; j < 4; ++j) {
    int idx = base + t * 4 + j;
    if (idx < n) rp[idx] = run;
    run += c[j];
  }
  if (t == 255) bsums[blockIdx.x] = sums[255];
}

__global__ void k_scan2(int* __restrict__ bsums, int nb) {
  __shared__ int s[256];
  int t = threadIdx.x;
  int v = (t < nb) ? bsums[t] : 0;
  s[t] = v;
  __syncthreads();
  for (int off = 1; off < 256; off <<= 1) {
    int u = 0;
    if (t >= off) u = s[t - off];
    __syncthreads();
    if (t >= off) s[t] += u;
    __syncthreads();
  }
  if (t < nb) bsums[t] = s[t] - v;  // exclusive
}

__global__ void k_scan3(int* __restrict__ rp, const int* __restrict__ bsums, int n, int E) {
  int idx = blockIdx.x * 256 + threadIdx.x;
  if (idx < n) rp[idx] += bsums[idx >> 10];
  if (idx == n) rp[n] = E;
}

// scatter edges to CSR order; pack (src, norm_bits) into int2
__global__ void k_scatter(const int* __restrict__ src, const int* __restrict__ dst,
                          const float* __restrict__ dis,
                          const int* __restrict__ rp, int* __restrict__ fill,
                          int2* __restrict__ epack, int E) {
  int e = blockIdx.x * 256 + threadIdx.x;
  if (e >= E) return;
  int d = dst[e], s = src[e];
  int pos = rp[d] + atomicAdd(&fill[d], 1);
  float nw = dis[s] * dis[d];
  epack[pos] = make_int2(s, __builtin_bit_cast(int, nw));
}

// ---------------- weight prep: W[K][128] f32 -> WT[128][KPAD] bf16 (zero-padded) ----------------

__global__ void k_prep_w(const float* __restrict__ W, short* __restrict__ WT, int K, int KPAD) {
  int idx = blockIdx.x * 256 + threadIdx.x;
  if (idx >= 128 * KPAD) return;
  int c = idx / KPAD, k = idx - c * KPAD;
  WT[idx] = (k < K) ? (short)f2bf_bits(W[(size_t)k * FH + c]) : (short)0;
}

// ---------------- MFMA GEMM: C[M][128](bf16) = A[M][K] @ WT^T ----------------
// BM=64, BN=128, BK=32, 256 threads (4 waves 2x2). Reg-staged prefetch:
// issue tile t+1 global loads right after the barrier, before tile t's
// ds_read + MFMA, so HBM latency hides under compute (2-phase pipeline).
// LDS rows at 80B stride (5x16B) -> b128 frag reads are conflict-benign.

template<bool AF32>
__global__ void __launch_bounds__(256) k_gemm_mfma(const void* __restrict__ Aptr,
                                                   const short* __restrict__ WT,
                                                   short* __restrict__ C,
                                                   int M, int K, int KPAD) {
  __shared__ char sA[64 * 80];
  __shared__ char sB[128 * 80];
  const int tid = threadIdx.x;
  const int r0 = blockIdx.x * 64;
  const int wave = tid >> 6, lane = tid & 63;
  const int wm = wave >> 1, wn = wave & 1;
  const int lr = lane & 15, g = lane >> 4;
  const int arow = tid >> 2, aq = tid & 3;   // A staging: row 0..63, 8 k-elems each
  const int bcol = tid >> 1, bh = tid & 1;   // B staging: col 0..127, 16 k-elems each

  f32x4 acc[2][4];
#pragma unroll
  for (int i = 0; i < 2; ++i)
#pragma unroll
    for (int j = 0; j < 4; ++j) acc[i][j] = (f32x4){0.f, 0.f, 0.f, 0.f};

  const int nkt = (K + 31) / 32;
  const int agr = (r0 + arow < M) ? (r0 + arow) : (M - 1);  // clamp; stores guarded

  // prefetch registers
  float4 fa0, fa1;   // AF32 path
  short8 abf;        // bf16 path
  short8 b0, b1;

  auto loadA = [&](int kt) {
    const int k0 = kt * 32 + aq * 8;
    if (AF32) {
      const float* A = (const float*)Aptr;
      if (k0 + 8 <= K) {
        const float4* ap = (const float4*)(A + (size_t)agr * K + k0);
        fa0 = ap[0]; fa1 = ap[1];
      } else {
        const float* ap = A + (size_t)agr * K;
        float t[8];
#pragma unroll
        for (int j = 0; j < 8; ++j) t[j] = (k0 + j < K) ? ap[k0 + j] : 0.f;
        fa0 = make_float4(t[0], t[1], t[2], t[3]);
        fa1 = make_float4(t[4], t[5], t[6], t[7]);
      }
    } else {
      const short* A = (const short*)Aptr;   // K multiple of 32, fully in-bounds
      abf = *(const short8*)(A + (size_t)agr * K + k0);
    }
  };
  auto loadB = [&](int kt) {
    const int k0 = kt * 32 + bh * 16;
    const short8* wp = (const short8*)(WT + (size_t)bcol * KPAD + k0);
    b0 = wp[0]; b1 = wp[1];
  };
  auto stageLDS = [&]() {
    short8 av;
    if (AF32) {
      float f[8] = {fa0.x, fa0.y, fa0.z, fa0.w, fa1.x, fa1.y, fa1.z, fa1.w};
#pragma unroll
      for (int j = 0; j < 8; ++j) av[j] = (short)f2bf_bits(f[j]);
    } else {
      av = abf;
    }
    *(short8*)(sA + arow * 80 + aq * 16) = av;
    *(short8*)(sB + bcol * 80 + bh * 32) = b0;
    *(short8*)(sB + bcol * 80 + bh * 32 + 16) = b1;
  };

  loadA(0); loadB(0);
  for (int kt = 0; kt < nkt; ++kt) {
    stageLDS();
    __syncthreads();
    if (kt + 1 < nkt) { loadA(kt + 1); loadB(kt + 1); }  // overlap with MFMA below
    short8 af[2], bfr[4];
#pragma unroll
    for (int i = 0; i < 2; ++i)
      af[i] = *(const short8*)(sA + (wm * 32 + i * 16 + lr) * 80 + g * 16);
#pragma unroll
    for (int j = 0; j < 4; ++j)
      bfr[j] = *(const short8*)(sB + (wn * 64 + j * 16 + lr) * 80 + g * 16);
#pragma unroll
    for (int i = 0; i < 2; ++i)
#pragma unroll
      for (int j = 0; j < 4; ++j)
        acc[i][j] = __builtin_amdgcn_mfma_f32_16x16x32_bf16(af[i], bfr[j], acc[i][j], 0, 0, 0);
    __syncthreads();
  }
  // epilogue: C/D layout col=lane&15, row=(lane>>4)*4+reg
#pragma unroll
  for (int i = 0; i < 2; ++i) {
#pragma unroll
    for (int reg = 0; reg < 4; ++reg) {
      int gr = r0 + wm * 32 + i * 16 + g * 4 + reg;
      if (gr < M) {
#pragma unroll
        for (int j = 0; j < 4; ++j) {
          int gc = wn * 64 + j * 16 + lr;
          C[(size_t)gr * FH + gc] = (short)f2bf_bits(acc[i][j][reg]);
        }
      }
    }
  }
}

// ---------------- aggregation (bf16 in/out, fp32 accum) ----------------
// one wave per node; lane covers features 2*lane, 2*lane+1 (256B/row = one
// coalesced wave load). Edges consumed 16 at a time: lanes 0..15 load the
// packs, __shfl(,const) broadcasts -> SGPR row addresses, 16 gathers in
// flight (MLP=16). Masked tail lanes contribute (src=0, norm=0): harmless
// L1-hot loads of row 0, zero numeric effect.

__global__ void __launch_bounds__(256) k_agg(const unsigned* __restrict__ h,
                                             unsigned* __restrict__ out,
                                             const float* __restrict__ dis,
                                             const int* __restrict__ rp,
                                             const int2* __restrict__ epack,
                                             const float* __restrict__ bias,
                                             int N) {
  int node = blockIdx.x * 4 + (threadIdx.x >> 6);
  int lane = threadIdx.x & 63;
  if (node >= N) return;
  float di = dis[node];
  unsigned sv = h[(size_t)node * 64 + lane];
  float w = di * di;
  float a0 = w * bf_lo(sv);
  float a1 = w * bf_hi(sv);
  const int end = rp[node + 1];
  for (int e = rp[node]; e < end; e += 16) {
    int rem = end - e;
    int2 p = make_int2(0, 0);
    if (lane < rem) p = epack[e + lane];
    unsigned vv[16]; float nn[16];
#pragma unroll
    for (int j = 0; j < 16; ++j) {
      int s = __shfl(p.x, j);
      nn[j] = __builtin_bit_cast(float, __shfl(p.y, j));
      vv[j] = h[(size_t)s * 64 + lane];
    }
#pragma unroll
    for (int j = 0; j < 16; ++j) {
      a0 += nn[j] * bf_lo(vv[j]);
      a1 += nn[j] * bf_hi(vv[j]);
    }
  }
  a0 = fmaxf(a0 + bias[2 * lane], 0.f);
  a1 = fmaxf(a1 + bias[2 * lane + 1], 0.f);
  unsigned r = ((unsigned)f2bf_bits(a1) << 16) | (unsigned)f2bf_bits(a0);
  out[(size_t)node * 64 + lane] = r;
}

// ---------------- fused logits + log_softmax (one wave per node) ----------------

__global__ void __launch_bounds__(256) k_logits(const unsigned* __restrict__ h,  // bf16 rows
                                                const float* __restrict__ Wfc,
                                                const float* __restrict__ bfc,
                                                float* __restrict__ out, int N) {
  int node = blockIdx.x * 4 + (threadIdx.x >> 6);
  int w = threadIdx.x >> 6;
  int l = threadIdx.x & 63;
  bool valid = node < N;
  int nclamp = valid ? node : (N - 1);
  __shared__ float hs[4][128];
  unsigned v = h[(size_t)nclamp * 64 + l];
  hs[w][2 * l] = bf_lo(v);
  hs[w][2 * l + 1] = bf_hi(v);
  __syncthreads();
  float logit = -INFINITY;
  if (l < FOUT) {
    float acc = bfc[l];
#pragma unroll 8
    for (int k = 0; k < FH; ++k) acc += hs[w][k] * Wfc[k * FOUT + l];
    logit = acc;
  }
  float m = logit;
#pragma unroll
  for (int s = 32; s; s >>= 1) m = fmaxf(m, __shfl_xor(m, s));
  float ex = (l < FOUT) ? expf(logit - m) : 0.0f;
  float ss = ex;
#pragma unroll
  for (int s = 32; s; s >>= 1) ss += __shfl_xor(ss, s);
  if (valid && l < FOUT) out[(size_t)node * FOUT + l] = logit - m - logf(ss);
}

// ---------------- host ----------------

static inline size_t align_up(size_t x, size_t a) { return (x + a - 1) & ~(a - 1); }

extern "C" void kernel_launch(void* const* d_in, const int* in_sizes, int n_in,
                              void* d_out, int out_size, void* d_ws, size_t ws_size,
                              hipStream_t stream) {
  const float* x   = (const float*)d_in[0];
  const int*   ei  = (const int*)d_in[1];
  const float* W0  = (const float*)d_in[2];
  const float* b0  = (const float*)d_in[3];
  const float* W1  = (const float*)d_in[4];
  const float* b1  = (const float*)d_in[5];
  const float* W2  = (const float*)d_in[6];
  const float* b2  = (const float*)d_in[7];
  const float* Wfc = (const float*)d_in[8];
  const float* bfc = (const float*)d_in[9];
  float* out = (float*)d_out;

  const int N = in_sizes[0] / FIN;       // 100000
  const int E = in_sizes[1] / 2;         // 1600000
  const int* src = ei;
  const int* dst = ei + E;
  const int KP0 = 512;                   // FIN padded to mult of 32

  // workspace layout
  char* ws = (char*)d_ws;
  size_t off = 0;
  int* cnt = (int*)(ws + off);            off = align_up(off + (size_t)N * 4, 512);
  float* dis = (float*)(ws + off);        off = align_up(off + (size_t)N * 4, 512);
  int* rp = (int*)(ws + off);             off = align_up(off + (size_t)(N + 1) * 4, 512);
  int* bsums = (int*)(ws + off);          off = align_up(off + 4096, 512);
  int2* epack = (int2*)(ws + off);        off = align_up(off + (size_t)E * 8, 512);
  short* WT0 = (short*)(ws + off);        off = align_up(off + (size_t)128 * KP0 * 2, 512);
  short* WT1 = (short*)(ws + off);        off = align_up(off + (size_t)128 * FH * 2, 512);
  short* WT2 = (short*)(ws + off);        off = align_up(off + (size_t)128 * FH * 2, 512);
  short* hA = (short*)(ws + off);         off = align_up(off + (size_t)N * FH * 2, 512);
  short* hB = (short*)(ws + off);         off = align_up(off + (size_t)N * FH * 2, 512);

  const int gE = (E + 255) / 256;
  const int gN = (N + 255) / 256;
  const int nbScan = (N + 1023) / 1024;

  // --- CSR build ---
  hipMemsetAsync(cnt, 0, (size_t)N * 4, stream);
  k_hist<<<gE, 256, 0, stream>>>(dst, cnt, E);
  k_dis<<<gN, 256, 0, stream>>>(cnt, dis, N);
  k_scan1<<<nbScan, 256, 0, stream>>>(cnt, rp, bsums, N);
  k_scan2<<<1, 256, 0, stream>>>(bsums, nbScan);
  k_scan3<<<(N + 1 + 255) / 256, 256, 0, stream>>>(rp, bsums, N, E);
  hipMemsetAsync(cnt, 0, (size_t)N * 4, stream);
  k_scatter<<<gE, 256, 0, stream>>>(src, dst, dis, rp, cnt, epack, E);

  // --- weight prep ---
  k_prep_w<<<(128 * KP0 + 255) / 256, 256, 0, stream>>>(W0, WT0, FIN, KP0);
  k_prep_w<<<(128 * FH + 255) / 256, 256, 0, stream>>>(W1, WT1, FH, FH);
  k_prep_w<<<(128 * FH + 255) / 256, 256, 0, stream>>>(W2, WT2, FH, FH);

  const int gGemm = (N + 63) / 64;
  const int gAgg = (N + 3) / 4;

  // --- layer 0: 500 -> 128 ---
  k_gemm_mfma<true><<<gGemm, 256, 0, stream>>>(x, WT0, hA, N, FIN, KP0);
  k_agg<<<gAgg, 256, 0, stream>>>((const unsigned*)hA, (unsigned*)hB, dis, rp, epack, b0, N);
  // --- layer 1 ---
  k_gemm_mfma<false><<<gGemm, 256, 0, stream>>>(hB, WT1, hA, N, FH, FH);
  k_agg<<<gAgg, 256, 0, stream>>>((const unsigned*)hA, (unsigned*)hB, dis, rp, epack, b1, N);
  // --- layer 2 ---
  k_gemm_mfma<false><<<gGemm, 256, 0, stream>>>(hB, WT2, hA, N, FH, FH);
  k_agg<<<gAgg, 256, 0, stream>>>((const unsigned*)hA, (unsigned*)hB, dis, rp, epack, b2, N);
  // --- FC + log_softmax ---
  k_logits<<<gAgg, 256, 0, stream>>>((const unsigned*)hB, Wfc, bfc, out, N);
}

// Round 4
// 479.876 us; speedup vs baseline: 2.4296x; 1.1385x over previous
//
#include <hip/hip_runtime.h>
#include <hip/hip_bf16.h>
#include <cstdint>
#include <cstddef>

#define FIN 500
#define FH  128
#define FOUT 40

typedef __attribute__((ext_vector_type(8))) short short8;
typedef __attribute__((ext_vector_type(4))) float f32x4;

__device__ inline float bf_lo(unsigned v) { unsigned t = v << 16; return __builtin_bit_cast(float, t); }
__device__ inline float bf_hi(unsigned v) { unsigned t = v & 0xffff0000u; return __builtin_bit_cast(float, t); }
__device__ inline unsigned short f2bf_bits(float f) {
  __hip_bfloat16 b = __float2bfloat16(f);
  return __builtin_bit_cast(unsigned short, b);
}

// ---------------- CSR build ----------------

__global__ void k_hist(const int* __restrict__ dst, int* __restrict__ cnt, int E) {
  int e = blockIdx.x * 256 + threadIdx.x;
  if (e < E) atomicAdd(&cnt[dst[e]], 1);
}

__global__ void k_dis(const int* __restrict__ cnt, float* __restrict__ dis, int n) {
  int i = blockIdx.x * 256 + threadIdx.x;
  if (i < n) dis[i] = rsqrtf((float)cnt[i] + 1.0f);  // deg includes self-loop
}

__global__ void k_scan1(const int* __restrict__ cnt, int* __restrict__ rp,
                        int* __restrict__ bsums, int n) {
  __shared__ int sums[256];
  int t = threadIdx.x;
  int base = blockIdx.x * 1024;
  int c[4]; int tot = 0;
#pragma unroll
  for (int j = 0; j < 4; ++j) {
    int idx = base + t * 4 + j;
    c[j] = (idx < n) ? cnt[idx] : 0;
    tot += c[j];
  }
  sums[t] = tot;
  __syncthreads();
  for (int off = 1; off < 256; off <<= 1) {
    int v = 0;
    if (t >= off) v = sums[t - off];
    __syncthreads();
    if (t >= off) sums[t] += v;
    __syncthreads();
  }
  int run = sums[t] - tot;
#pragma unroll
  for (int j = 0; j < 4; ++j) {
    int idx = base + t * 4 + j;
    if (idx < n) rp[idx] = run;
    run += c[j];
  }
  if (t == 255) bsums[blockIdx.x] = sums[255];
}

__global__ void k_scan2(int* __restrict__ bsums, int nb) {
  __shared__ int s[256];
  int t = threadIdx.x;
  int v = (t < nb) ? bsums[t] : 0;
  s[t] = v;
  __syncthreads();
  for (int off = 1; off < 256; off <<= 1) {
    int u = 0;
    if (t >= off) u = s[t - off];
    __syncthreads();
    if (t >= off) s[t] += u;
    __syncthreads();
  }
  if (t < nb) bsums[t] = s[t] - v;  // exclusive
}

__global__ void k_scan3(int* __restrict__ rp, const int* __restrict__ bsums, int n, int E) {
  int idx = blockIdx.x * 256 + threadIdx.x;
  if (idx < n) rp[idx] += bsums[idx >> 10];
  if (idx == n) rp[n] = E;
}

// scatter edges to CSR order; pack (src_byte_offset, norm_bits) into int2
__global__ void k_scatter(const int* __restrict__ src, const int* __restrict__ dst,
                          const float* __restrict__ dis,
                          const int* __restrict__ rp, int* __restrict__ fill,
                          int2* __restrict__ epack, int E) {
  int e = blockIdx.x * 256 + threadIdx.x;
  if (e >= E) return;
  int d = dst[e], s = src[e];
  int pos = rp[d] + atomicAdd(&fill[d], 1);
  float nw = dis[s] * dis[d];
  epack[pos] = make_int2(s << 8, __builtin_bit_cast(int, nw));  // s*256 = row byte offset
}

// ---------------- weight prep ----------------

__global__ void k_prep_w(const float* __restrict__ W, short* __restrict__ WT, int K, int KPAD) {
  int idx = blockIdx.x * 256 + threadIdx.x;
  if (idx >= 128 * KPAD) return;
  int c = idx / KPAD, k = idx - c * KPAD;
  WT[idx] = (k < K) ? (short)f2bf_bits(W[(size_t)k * FH + c]) : (short)0;
}

// WfcT[48][128] bf16 from Wfc[128][40] f32, zero-padded cols 40..47
__global__ void k_prep_wfc(const float* __restrict__ Wfc, short* __restrict__ WfcT) {
  int idx = blockIdx.x * 256 + threadIdx.x;
  if (idx >= 48 * 128) return;
  int c = idx >> 7, k = idx & 127;
  WfcT[idx] = (c < FOUT) ? (short)f2bf_bits(Wfc[(size_t)k * FOUT + c]) : (short)0;
}

// ---------------- MFMA GEMM: C[M][128](bf16) = A[M][K] @ WT^T ----------------
// BM=64, BN=128, BK=32, 256 threads (4 waves 2x2). Double-buffered LDS:
// one barrier per K-step; tile t+1 global loads issued before tile t's MFMA,
// staged into the other buffer after MFMA. LDS rows at 80B stride.

template<bool AF32>
__global__ void __launch_bounds__(256) k_gemm_mfma(const void* __restrict__ Aptr,
                                                   const short* __restrict__ WT,
                                                   short* __restrict__ C,
                                                   int M, int K, int KPAD) {
  __shared__ char sA[2][64 * 80];
  __shared__ char sB[2][128 * 80];
  const int tid = threadIdx.x;
  const int r0 = blockIdx.x * 64;
  const int wave = tid >> 6, lane = tid & 63;
  const int wm = wave >> 1, wn = wave & 1;
  const int lr = lane & 15, g = lane >> 4;
  const int arow = tid >> 2, aq = tid & 3;   // A staging: row 0..63, 8 k-elems each
  const int bcol = tid >> 1, bh = tid & 1;   // B staging: col 0..127, 16 k-elems each

  f32x4 acc[2][4];
#pragma unroll
  for (int i = 0; i < 2; ++i)
#pragma unroll
    for (int j = 0; j < 4; ++j) acc[i][j] = (f32x4){0.f, 0.f, 0.f, 0.f};

  const int nkt = (K + 31) / 32;
  const int agr = (r0 + arow < M) ? (r0 + arow) : (M - 1);  // clamp; stores guarded

  float4 fa0, fa1;   // AF32 prefetch regs
  short8 abf;        // bf16 prefetch
  short8 b0, b1;

  auto loadA = [&](int kt) {
    const int k0 = kt * 32 + aq * 8;
    if (AF32) {
      const float* A = (const float*)Aptr;
      if (k0 + 8 <= K) {
        const float4* ap = (const float4*)(A + (size_t)agr * K + k0);
        fa0 = ap[0]; fa1 = ap[1];
      } else {
        const float* ap = A + (size_t)agr * K;
        float t[8];
#pragma unroll
        for (int j = 0; j < 8; ++j) t[j] = (k0 + j < K) ? ap[k0 + j] : 0.f;
        fa0 = make_float4(t[0], t[1], t[2], t[3]);
        fa1 = make_float4(t[4], t[5], t[6], t[7]);
      }
    } else {
      const short* A = (const short*)Aptr;   // K multiple of 32
      abf = *(const short8*)(A + (size_t)agr * K + k0);
    }
  };
  auto loadB = [&](int kt) {
    const int k0 = kt * 32 + bh * 16;
    const short8* wp = (const short8*)(WT + (size_t)bcol * KPAD + k0);
    b0 = wp[0]; b1 = wp[1];
  };
  auto stageLDS = [&](int buf) {
    short8 av;
    if (AF32) {
      float f[8] = {fa0.x, fa0.y, fa0.z, fa0.w, fa1.x, fa1.y, fa1.z, fa1.w};
#pragma unroll
      for (int j = 0; j < 8; ++j) av[j] = (short)f2bf_bits(f[j]);
    } else {
      av = abf;
    }
    *(short8*)(sA[buf] + arow * 80 + aq * 16) = av;
    *(short8*)(sB[buf] + bcol * 80 + bh * 32) = b0;
    *(short8*)(sB[buf] + bcol * 80 + bh * 32 + 16) = b1;
  };

  loadA(0); loadB(0);
  stageLDS(0);
  __syncthreads();
  for (int kt = 0; kt < nkt; ++kt) {
    const int cur = kt & 1;
    if (kt + 1 < nkt) { loadA(kt + 1); loadB(kt + 1); }
    short8 af[2], bfr[4];
#pragma unroll
    for (int i = 0; i < 2; ++i)
      af[i] = *(const short8*)(sA[cur] + (wm * 32 + i * 16 + lr) * 80 + g * 16);
#pragma unroll
    for (int j = 0; j < 4; ++j)
      bfr[j] = *(const short8*)(sB[cur] + (wn * 64 + j * 16 + lr) * 80 + g * 16);
#pragma unroll
    for (int i = 0; i < 2; ++i)
#pragma unroll
      for (int j = 0; j < 4; ++j)
        acc[i][j] = __builtin_amdgcn_mfma_f32_16x16x32_bf16(af[i], bfr[j], acc[i][j], 0, 0, 0);
    if (kt + 1 < nkt) stageLDS(cur ^ 1);
    __syncthreads();
  }
  // epilogue: C/D layout col=lane&15, row=(lane>>4)*4+reg
#pragma unroll
  for (int i = 0; i < 2; ++i) {
#pragma unroll
    for (int reg = 0; reg < 4; ++reg) {
      int gr = r0 + wm * 32 + i * 16 + g * 4 + reg;
      if (gr < M) {
#pragma unroll
        for (int j = 0; j < 4; ++j) {
          int gc = wn * 64 + j * 16 + lr;
          C[(size_t)gr * FH + gc] = (short)f2bf_bits(acc[i][j][reg]);
        }
      }
    }
  }
}

// ---------------- aggregation v3 (bf16 in/out, fp32 accum) ----------------
// One wave per node. 2 edges per gather instruction: lanes 0-31 take the even
// edge, 32-63 the odd edge; each lane loads uint2 (4 features). Edge packs are
// loaded by lanes 0-15 and distributed via ds_bpermute. Final shfl_xor(32)
// combines the two edge-parity halves. epack.x is a precomputed byte offset.

__global__ void __launch_bounds__(256) k_agg(const char* __restrict__ hbytes,
                                             char* __restrict__ outbytes,
                                             const float* __restrict__ dis,
                                             const int* __restrict__ rp,
                                             const int2* __restrict__ epack,
                                             const float* __restrict__ bias,
                                             int N) {
  int node = blockIdx.x * 4 + (threadIdx.x >> 6);
  int lane = threadIdx.x & 63;
  if (node >= N) return;
  const int q = lane & 31;       // uint2 index within the 256B row
  const int hi = lane >> 5;      // 0: even edges, 1: odd edges
  const int q8 = q * 8;
  float a0 = 0.f, a1 = 0.f, a2 = 0.f, a3 = 0.f;
  if (hi == 0) {                 // self term once (halves are summed later)
    float w = dis[node]; w = w * w;
    uint2 sv = *(const uint2*)(hbytes + (size_t)node * 256 + q8);
    a0 = w * bf_lo(sv.x); a1 = w * bf_hi(sv.x);
    a2 = w * bf_lo(sv.y); a3 = w * bf_hi(sv.y);
  }
  const int vbp = hi * 4;        // ds_bpermute byte addr: lane 2j+hi
  const int end = rp[node + 1];
  for (int e = rp[node]; e < end; e += 16) {
    int rem = end - e;
    int2 p = make_int2(0, 0);
    if (lane < 16 && lane < rem) p = epack[e + lane];
    uint2 vv[8]; float nn[8];
#pragma unroll
    for (int j = 0; j < 8; ++j) {
      int idx4 = vbp + 8 * j;
      int off = __builtin_amdgcn_ds_bpermute(idx4, p.x);
      int nb  = __builtin_amdgcn_ds_bpermute(idx4, p.y);
      nn[j] = __builtin_bit_cast(float, nb);
      vv[j] = *(const uint2*)(hbytes + (size_t)(unsigned)(off + q8));
    }
#pragma unroll
    for (int j = 0; j < 8; ++j) {
      a0 += nn[j] * bf_lo(vv[j].x); a1 += nn[j] * bf_hi(vv[j].x);
      a2 += nn[j] * bf_lo(vv[j].y); a3 += nn[j] * bf_hi(vv[j].y);
    }
  }
  a0 += __shfl_xor(a0, 32); a1 += __shfl_xor(a1, 32);
  a2 += __shfl_xor(a2, 32); a3 += __shfl_xor(a3, 32);
  if (hi == 0) {
    float4 bv = *(const float4*)(bias + 4 * q);
    a0 = fmaxf(a0 + bv.x, 0.f); a1 = fmaxf(a1 + bv.y, 0.f);
    a2 = fmaxf(a2 + bv.z, 0.f); a3 = fmaxf(a3 + bv.w, 0.f);
    uint2 r;
    r.x = ((unsigned)f2bf_bits(a1) << 16) | (unsigned)f2bf_bits(a0);
    r.y = ((unsigned)f2bf_bits(a3) << 16) | (unsigned)f2bf_bits(a2);
    *(uint2*)(outbytes + (size_t)node * 256 + q8) = r;
  }
}

// ---------------- fused logits + log_softmax via MFMA ----------------
// 64 nodes/block, wave handles 16 nodes x 48 classes (40 valid) with 12
// 16x16x32 MFMAs; softmax reduced over 16-lane groups via shfl_xor.

__global__ void __launch_bounds__(256) k_logits(const short* __restrict__ h,     // bf16 [N][128]
                                                const short* __restrict__ WfcT,  // bf16 [48][128]
                                                const float* __restrict__ bfc,
                                                float* __restrict__ out, int N) {
  const int wave = threadIdx.x >> 6, lane = threadIdx.x & 63;
  const int lr = lane & 15, g = lane >> 4;
  const int nbase = blockIdx.x * 64 + wave * 16;
  int arow = nbase + lr; if (arow >= N) arow = N - 1;
  const short* ap = h + (size_t)arow * FH;
  short8 af[4];
#pragma unroll
  for (int ks = 0; ks < 4; ++ks)
    af[ks] = *(const short8*)(ap + ks * 32 + g * 8);
  f32x4 acc[3];
#pragma unroll
  for (int t = 0; t < 3; ++t) {
    acc[t] = (f32x4){0.f, 0.f, 0.f, 0.f};
    const short* bp = WfcT + (size_t)(t * 16 + lr) * FH;
#pragma unroll
    for (int ks = 0; ks < 4; ++ks) {
      short8 bf = *(const short8*)(bp + ks * 32 + g * 8);
      acc[t] = __builtin_amdgcn_mfma_f32_16x16x32_bf16(af[ks], bf, acc[t], 0, 0, 0);
    }
  }
  float bb[3];
#pragma unroll
  for (int t = 0; t < 3; ++t) { int c = t * 16 + lr; bb[t] = (c < FOUT) ? bfc[c] : 0.f; }
  const bool v2 = (lr < 8);  // tile 2 valid classes: 32..39
  float res[3][4];
#pragma unroll
  for (int r = 0; r < 4; ++r) {
    float l0 = acc[0][r] + bb[0];
    float l1 = acc[1][r] + bb[1];
    float l2 = v2 ? (acc[2][r] + bb[2]) : -INFINITY;
    float mm = fmaxf(fmaxf(l0, l1), l2);
#pragma unroll
    for (int s = 1; s < 16; s <<= 1) mm = fmaxf(mm, __shfl_xor(mm, s));
    float e0 = expf(l0 - mm), e1 = expf(l1 - mm), e2 = v2 ? expf(l2 - mm) : 0.f;
    float ss = e0 + e1 + e2;
#pragma unroll
    for (int s = 1; s < 16; s <<= 1) ss += __shfl_xor(ss, s);
    float lse = mm + logf(ss);
    res[0][r] = l0 - lse; res[1][r] = l1 - lse; res[2][r] = l2 - lse;
  }
#pragma unroll
  for (int t = 0; t < 3; ++t) {
    int c = t * 16 + lr;
    if (c < FOUT) {
#pragma unroll
      for (int r = 0; r < 4; ++r) {
        int node = nbase + g * 4 + r;
        if (node < N) out[(size_t)node * FOUT + c] = res[t][r];
      }
    }
  }
}

// ---------------- host ----------------

static inline size_t align_up(size_t x, size_t a) { return (x + a - 1) & ~(a - 1); }

extern "C" void kernel_launch(void* const* d_in, const int* in_sizes, int n_in,
                              void* d_out, int out_size, void* d_ws, size_t ws_size,
                              hipStream_t stream) {
  const float* x   = (const float*)d_in[0];
  const int*   ei  = (const int*)d_in[1];
  const float* W0  = (const float*)d_in[2];
  const float* b0  = (const float*)d_in[3];
  const float* W1  = (const float*)d_in[4];
  const float* b1  = (const float*)d_in[5];
  const float* W2  = (const float*)d_in[6];
  const float* b2  = (const float*)d_in[7];
  const float* Wfc = (const float*)d_in[8];
  const float* bfc = (const float*)d_in[9];
  float* out = (float*)d_out;

  const int N = in_sizes[0] / FIN;       // 100000
  const int E = in_sizes[1] / 2;         // 1600000
  const int* src = ei;
  const int* dst = ei + E;
  const int KP0 = 512;                   // FIN padded to mult of 32

  // workspace layout
  char* ws = (char*)d_ws;
  size_t off = 0;
  int* cnt = (int*)(ws + off);            off = align_up(off + (size_t)N * 4, 512);
  float* dis = (float*)(ws + off);        off = align_up(off + (size_t)N * 4, 512);
  int* rp = (int*)(ws + off);             off = align_up(off + (size_t)(N + 1) * 4, 512);
  int* bsums = (int*)(ws + off);          off = align_up(off + 4096, 512);
  int2* epack = (int2*)(ws + off);        off = align_up(off + (size_t)E * 8, 512);
  short* WT0 = (short*)(ws + off);        off = align_up(off + (size_t)128 * KP0 * 2, 512);
  short* WT1 = (short*)(ws + off);        off = align_up(off + (size_t)128 * FH * 2, 512);
  short* WT2 = (short*)(ws + off);        off = align_up(off + (size_t)128 * FH * 2, 512);
  short* WfcT = (short*)(ws + off);       off = align_up(off + (size_t)48 * FH * 2, 512);
  short* hA = (short*)(ws + off);         off = align_up(off + (size_t)N * FH * 2, 512);
  short* hB = (short*)(ws + off);         off = align_up(off + (size_t)N * FH * 2, 512);

  const int gE = (E + 255) / 256;
  const int gN = (N + 255) / 256;
  const int nbScan = (N + 1023) / 1024;

  // --- CSR build ---
  hipMemsetAsync(cnt, 0, (size_t)N * 4, stream);
  k_hist<<<gE, 256, 0, stream>>>(dst, cnt, E);
  k_dis<<<gN, 256, 0, stream>>>(cnt, dis, N);
  k_scan1<<<nbScan, 256, 0, stream>>>(cnt, rp, bsums, N);
  k_scan2<<<1, 256, 0, stream>>>(bsums, nbScan);
  k_scan3<<<(N + 1 + 255) / 256, 256, 0, stream>>>(rp, bsums, N, E);
  hipMemsetAsync(cnt, 0, (size_t)N * 4, stream);
  k_scatter<<<gE, 256, 0, stream>>>(src, dst, dis, rp, cnt, epack, E);

  // --- weight prep ---
  k_prep_w<<<(128 * KP0 + 255) / 256, 256, 0, stream>>>(W0, WT0, FIN, KP0);
  k_prep_w<<<(128 * FH + 255) / 256, 256, 0, stream>>>(W1, WT1, FH, FH);
  k_prep_w<<<(128 * FH + 255) / 256, 256, 0, stream>>>(W2, WT2, FH, FH);
  k_prep_wfc<<<(48 * FH + 255) / 256, 256, 0, stream>>>(Wfc, WfcT);

  const int gGemm = (N + 63) / 64;
  const int gAgg = (N + 3) / 4;
  const int gLog = (N + 63) / 64;

  // --- layer 0: 500 -> 128 ---
  k_gemm_mfma<true><<<gGemm, 256, 0, stream>>>(x, WT0, hA, N, FIN, KP0);
  k_agg<<<gAgg, 256, 0, stream>>>((const char*)hA, (char*)hB, dis, rp, epack, b0, N);
  // --- layer 1 ---
  k_gemm_mfma<false><<<gGemm, 256, 0, stream>>>(hB, WT1, hA, N, FH, FH);
  k_agg<<<gAgg, 256, 0, stream>>>((const char*)hA, (char*)hB, dis, rp, epack, b1, N);
  // --- layer 2 ---
  k_gemm_mfma<false><<<gGemm, 256, 0, stream>>>(hB, WT2, hA, N, FH, FH);
  k_agg<<<gAgg, 256, 0, stream>>>((const char*)hA, (char*)hB, dis, rp, epack, b2, N);
  // --- FC + log_softmax ---
  k_logits<<<gLog, 256, 0, stream>>>(hB, WfcT, bfc, out, N);
}